// Round 5
// baseline (7079.981 us; speedup 1.0000x reference)
//
#include <hip/hip_runtime.h>
#include <math.h>

#define Bsz 64
#define Tn 64
#define Ln 100
#define Dn 128
#define An 18
#define Hn 512

__device__ __forceinline__ float sigf(float x){ return 1.0f/(1.0f+expf(-x)); }

// write-through agent-scope store (reaches coherence point; no stale dirty line)
__device__ __forceinline__ void scst(float* p, float v){
  __hip_atomic_store(p, v, __ATOMIC_RELAXED, __HIP_MEMORY_SCOPE_AGENT);
}

// grid barrier: relaxed bypass atomics only. vmcnt(0) drains this block's
// write-through stores to the coherence point before arrival. Readers use
// normal cached loads of WRITE-ONCE addresses (never cached pre-write), so
// no acquire fence / L2 invalidate is needed.
__device__ __forceinline__ void gbar(int* arrive, int* gen, int nb, int ph){
  __syncthreads();
  if (threadIdx.x == 0){
    asm volatile("s_waitcnt vmcnt(0) lgkmcnt(0)" ::: "memory");
    int a = __hip_atomic_fetch_add(arrive, 1, __ATOMIC_RELAXED, __HIP_MEMORY_SCOPE_AGENT) + 1;
    if (a == nb*ph){
      __hip_atomic_store(gen, ph, __ATOMIC_RELAXED, __HIP_MEMORY_SCOPE_AGENT);
    } else {
      while (__hip_atomic_load(gen, __ATOMIC_RELAXED, __HIP_MEMORY_SCOPE_AGENT) < ph)
        __builtin_amdgcn_s_sleep(2);
    }
  }
  __syncthreads();
}

// ---------- demo transpose: demoT[l][b][d] = demo[0][b][l][d] ----------
__global__ __launch_bounds__(256) void demo_transpose_kernel(
    const float* __restrict__ demo, float* __restrict__ demoT)
{
  int idx = blockIdx.x*256 + threadIdx.x;   // ((l*64 + b)*128 + d)
  if (idx < Ln*Bsz*Dn) {
    int d = idx & 127;
    int b = (idx >> 7) & 63;
    int l = idx >> 13;
    demoT[idx] = demo[((size_t)(b*Ln + l))*Dn + d];
  }
}

// ---------- generic tiled GEMM: C[M][N] = A[M][K] * B[N][K]^T + bias[n] ----------
__global__ __launch_bounds__(256) void gemm_nt_kernel(
    const float* __restrict__ A, int lda,
    const float* __restrict__ B, int ldb,
    const float* __restrict__ bias,
    float* __restrict__ C, int ldc, int K)
{
  __shared__ float As[64][17];
  __shared__ float Bs[64][17];
  const int m0 = blockIdx.x * 64;
  const int n0 = blockIdx.y * 64;
  const int tx = threadIdx.x & 15;
  const int ty = threadIdx.x >> 4;
  float acc[4][4] = {};
  for (int k0 = 0; k0 < K; k0 += 16) {
    #pragma unroll
    for (int i = 0; i < 4; i++) {
      int e = threadIdx.x + i*256;
      int r = e >> 4, c = e & 15;
      As[r][c] = A[(size_t)(m0 + r)*lda + k0 + c];
      Bs[r][c] = B[(size_t)(n0 + r)*ldb + k0 + c];
    }
    __syncthreads();
    #pragma unroll
    for (int kk = 0; kk < 16; kk++) {
      float a0 = As[ty*4+0][kk], a1 = As[ty*4+1][kk], a2 = As[ty*4+2][kk], a3 = As[ty*4+3][kk];
      float b0 = Bs[tx*4+0][kk], b1 = Bs[tx*4+1][kk], b2 = Bs[tx*4+2][kk], b3 = Bs[tx*4+3][kk];
      acc[0][0] += a0*b0; acc[0][1] += a0*b1; acc[0][2] += a0*b2; acc[0][3] += a0*b3;
      acc[1][0] += a1*b0; acc[1][1] += a1*b1; acc[1][2] += a1*b2; acc[1][3] += a1*b3;
      acc[2][0] += a2*b0; acc[2][1] += a2*b1; acc[2][2] += a2*b2; acc[2][3] += a2*b3;
      acc[3][0] += a3*b0; acc[3][1] += a3*b1; acc[3][2] += a3*b2; acc[3][3] += a3*b3;
    }
    __syncthreads();
  }
  #pragma unroll
  for (int i = 0; i < 4; i++) {
    #pragma unroll
    for (int j = 0; j < 4; j++) {
      int nn = n0 + tx*4 + j;
      float v = acc[i][j] + (bias ? bias[nn] : 0.0f);
      C[(size_t)(m0 + ty*4 + i)*ldc + nn] = v;
    }
  }
}

// ---------- persistent fused encoder: h-scan + attnp + CE, 256 blocks x 2 cols ----------
__global__ __launch_bounds__(256, 1) void enc_scan_kernel(
    const float* __restrict__ demoT,   // [Ln][Bsz][Dn]
    const float* __restrict__ Wih, const float* __restrict__ Whh,
    const float* __restrict__ bih, const float* __restrict__ bhh,
    const float* __restrict__ attn_W, const float* __restrict__ attn_b,
    const float* __restrict__ comb_W,
    float* __restrict__ hencR,         // [Ln][Bsz][Hn]  per-step write-once
    float* __restrict__ attnp,         // [Bsz][Ln][Hn]
    float* __restrict__ CE,            // [Bsz][Hn][Ln]
    int* __restrict__ bar)
{
  const int bid  = blockIdx.x;
  const int lane = threadIdx.x & 63;
  const int ks   = threadIdx.x >> 6;
  const int n0 = bid*2;

  const float4* whh[8]; const float4* wih[8];
  #pragma unroll
  for (int c = 0; c < 2; c++)
    #pragma unroll
    for (int g = 0; g < 4; g++){
      int r = g*Hn + n0 + c;
      whh[c*4+g] = (const float4*)(Whh + (size_t)r*Hn) + ks*32;
      wih[c*4+g] = (const float4*)(Wih + (size_t)r*Dn) + ks*8;
    }
  const float4* atw[2] = {
    (const float4*)(attn_W + (size_t)(n0+0)*Hn) + ks*32,
    (const float4*)(attn_W + (size_t)(n0+1)*Hn) + ks*32 };
  const float4* cbw[2] = {
    (const float4*)(comb_W + (size_t)(n0+0)*(Hn+Dn)) + ks*32,
    (const float4*)(comb_W + (size_t)(n0+1)*(Hn+Dn)) + ks*32 };

  float bsum[2][4];
  #pragma unroll
  for (int c = 0; c < 2; c++)
    #pragma unroll
    for (int g = 0; g < 4; g++){
      int r = g*Hn + n0 + c;
      bsum[c][g] = bih[r] + bhh[r];
    }
  const float ab[2] = { attn_b[n0], attn_b[n0+1] };
  float cr[2] = {0.f, 0.f};

  __shared__ float red[4][12][Bsz];

  for (int l = 0; l <= Ln; l++){
    float a[2][4] = {{0,0,0,0},{0,0,0,0}};
    float aa[2] = {0,0}, ac[2] = {0,0};
    if (l >= 1){
      // cached float4 reads: lane streams its own batch row of h(l-1)
      const float4* hv = (const float4*)(hencR + ((size_t)(l-1)*Bsz + lane)*Hn) + ks*32;
      #pragma unroll 4
      for (int q = 0; q < 32; q++){
        float4 V = hv[q];
        #pragma unroll
        for (int c = 0; c < 2; c++){
          #pragma unroll
          for (int g = 0; g < 4; g++){
            float4 W = whh[c*4+g][q];
            a[c][g] += V.x*W.x + V.y*W.y + V.z*W.z + V.w*W.w;
          }
          float4 Aw = atw[c][q];
          aa[c] += V.x*Aw.x + V.y*Aw.y + V.z*Aw.z + V.w*Aw.w;
          float4 Cw = cbw[c][q];
          ac[c] += V.x*Cw.x + V.y*Cw.y + V.z*Cw.z + V.w*Cw.w;
        }
      }
    }
    if (l < Ln){
      const float4* dv = (const float4*)(demoT + ((size_t)l*Bsz + lane)*Dn) + ks*8;
      #pragma unroll
      for (int q = 0; q < 8; q++){
        float4 V = dv[q];
        #pragma unroll
        for (int c = 0; c < 2; c++)
          #pragma unroll
          for (int g = 0; g < 4; g++){
            float4 W = wih[c*4+g][q];
            a[c][g] += V.x*W.x + V.y*W.y + V.z*W.z + V.w*W.w;
          }
      }
    }
    #pragma unroll
    for (int c = 0; c < 2; c++){
      #pragma unroll
      for (int g = 0; g < 4; g++) red[ks][c*4+g][lane] = a[c][g];
      red[ks][8+c][lane]  = aa[c];
      red[ks][10+c][lane] = ac[c];
    }
    __syncthreads();
    if (threadIdx.x < Bsz){
      int b = threadIdx.x;
      if (l < Ln){
        #pragma unroll
        for (int c = 0; c < 2; c++){
          float g0 = red[0][c*4+0][b]+red[1][c*4+0][b]+red[2][c*4+0][b]+red[3][c*4+0][b] + bsum[c][0];
          float g1 = red[0][c*4+1][b]+red[1][c*4+1][b]+red[2][c*4+1][b]+red[3][c*4+1][b] + bsum[c][1];
          float g2 = red[0][c*4+2][b]+red[1][c*4+2][b]+red[2][c*4+2][b]+red[3][c*4+2][b] + bsum[c][2];
          float g3 = red[0][c*4+3][b]+red[1][c*4+3][b]+red[2][c*4+3][b]+red[3][c*4+3][b] + bsum[c][3];
          float ii = sigf(g0), ff = sigf(g1), gg = tanhf(g2), oo = sigf(g3);
          float cn = ff*cr[c] + ii*gg;
          float hn = oo*tanhf(cn);
          cr[c] = cn;
          scst(hencR + ((size_t)l*Bsz + b)*Hn + n0 + c, hn);
        }
      }
      if (l >= 1){
        #pragma unroll
        for (int c = 0; c < 2; c++){
          float av = red[0][8+c][b]+red[1][8+c][b]+red[2][8+c][b]+red[3][8+c][b] + ab[c];
          float cv = red[0][10+c][b]+red[1][10+c][b]+red[2][10+c][b]+red[3][10+c][b];
          scst(attnp + ((size_t)(b*Ln + (l-1)))*Hn + n0 + c, av);
          scst(CE + ((size_t)(b*Hn + n0 + c))*Ln + (l-1), cv);
        }
      }
    }
    if (l < Ln) gbar(bar+0, bar+1, (int)gridDim.x, l+1);
  }
}

// ---------- persistent decoder: 256 blocks, 2 phases/step ----------
__global__ __launch_bounds__(256, 1) void dec_scan_kernel(
    const float* __restrict__ h0, const float* __restrict__ c0,
    const float* __restrict__ attnp,   // [Bsz][Ln][Hn]
    const float* __restrict__ CE,      // [Bsz][Hn][Ln]
    const float* __restrict__ preobs,  // [Tn*Bsz][Hn]
    const int*   __restrict__ dlen,
    const float* __restrict__ lstm_Wih, const float* __restrict__ lstm_Whh,
    const float* __restrict__ lstm_bih, const float* __restrict__ lstm_bhh,
    const float* __restrict__ comb_b,
    float* __restrict__ xrow,          // [Tn][Bsz][Hn]  per-step write-once
    float* __restrict__ hhist,         // [Tn][Bsz][Hn]  per-step write-once
    float* __restrict__ outp,
    int* __restrict__ bar)
{
  const int bid  = blockIdx.x;
  const int tid  = threadIdx.x;
  const int lane = tid & 63;
  const int ks   = tid >> 6;
  const int n0 = bid*2;

  __shared__ float hs[Hn];
  __shared__ float wls[128];
  __shared__ float mx_s, sum_s;
  __shared__ float red[4][8][Bsz];

  const float4* wi[8]; const float4* wh[8];
  #pragma unroll
  for (int c = 0; c < 2; c++)
    #pragma unroll
    for (int g = 0; g < 4; g++){
      int r = g*Hn + n0 + c;
      wi[c*4+g] = (const float4*)(lstm_Wih + (size_t)r*Hn) + ks*32;
      wh[c*4+g] = (const float4*)(lstm_Whh + (size_t)r*Hn) + ks*32;
    }
  float bs[2][4];
  #pragma unroll
  for (int c = 0; c < 2; c++)
    #pragma unroll
    for (int g = 0; g < 4; g++){
      int r = g*Hn + n0 + c;
      bs[c][g] = lstm_bih[r] + lstm_bhh[r];
    }
  float cr[2] = {0.f, 0.f};
  int ph = 0;

  for (int t = 0; t < Tn; t++){
    const float* hprev_all = (t == 0) ? h0 : (hhist + (size_t)(t-1)*Bsz*Hn);

    // ============ Phase 1: attention scores + softmax + x (blocks 0..63) ============
    if (bid < Bsz){
      const int b = bid;
      const float* hrow = hprev_all + (size_t)b*Hn;
      for (int i = tid; i < Hn; i += 256) hs[i] = hrow[i];
      if (tid >= 200 && tid < 228) wls[tid - 100] = -1e30f;
      __syncthreads();
      const int len = dlen[b];
      if (tid < 200){
        int l = tid >> 1, kh = tid & 1;
        const float4* ap = (const float4*)(attnp + ((size_t)(b*Ln + l))*Hn + kh*256);
        const float4* hv = (const float4*)(hs + kh*256);
        float s = 0.f;
        #pragma unroll 8
        for (int k = 0; k < 64; k++){
          float4 A = ap[k], H = hv[k];
          s += A.x*H.x + A.y*H.y + A.z*H.z + A.w*H.w;
        }
        s += __shfl_xor(s, 1);
        if (kh == 0) wls[l] = (l < len) ? s*0.1f : -1e30f;
      }
      __syncthreads();
      if (tid < 64){
        float v = fmaxf(wls[tid], wls[tid+64]);
        for (int off = 1; off < 64; off <<= 1) v = fmaxf(v, __shfl_xor(v, off));
        if (tid == 0) mx_s = v;
      }
      __syncthreads();
      float mx = mx_s;
      if (tid < 64){
        float e0 = (wls[tid]    > -1e29f) ? expf(wls[tid]    - mx) : 0.f;
        float e1 = (wls[tid+64] > -1e29f) ? expf(wls[tid+64] - mx) : 0.f;
        wls[tid] = e0; wls[tid+64] = e1;
        float v = e0 + e1;
        for (int off = 1; off < 64; off <<= 1) v += __shfl_xor(v, off);
        if (tid == 0) sum_s = v;
      }
      __syncthreads();
      float inv = 1.0f / sum_s;
      const float* pr = preobs + ((size_t)(t*Bsz + b))*Hn;
      #pragma unroll
      for (int c2 = 0; c2 < 2; c2++){
        int n = tid + c2*256;
        const float* cer = CE + ((size_t)(b*Hn + n))*Ln;
        float acc = 0.f;
        for (int l2 = 0; l2 < len; ++l2) acc += cer[l2]*wls[l2];
        float v = acc*inv + pr[n] + comb_b[n];
        scst(xrow + ((size_t)t*Bsz + b)*Hn + n, fmaxf(v, 0.f));
      }
    }
    gbar(bar+2, bar+3, (int)gridDim.x, ++ph);

    // ============ Phase 2: gates = Wih@x + Whh@h_prev + bias; cell ============
    {
      float a[2][4] = {{0,0,0,0},{0,0,0,0}};
      // cached float4 streams: lane reads its own batch row of x(t) and h(t-1)
      const float4* xv = (const float4*)(xrow + ((size_t)t*Bsz + lane)*Hn) + ks*32;
      const float4* hv = (const float4*)(hprev_all + (size_t)lane*Hn) + ks*32;
      #pragma unroll 4
      for (int q = 0; q < 32; q++){
        float4 X = xv[q];
        float4 H = hv[q];
        #pragma unroll
        for (int c = 0; c < 2; c++)
          #pragma unroll
          for (int g = 0; g < 4; g++){
            float4 Wx = wi[c*4+g][q];
            float4 Wh = wh[c*4+g][q];
            a[c][g] += X.x*Wx.x + X.y*Wx.y + X.z*Wx.z + X.w*Wx.w
                     + H.x*Wh.x + H.y*Wh.y + H.z*Wh.z + H.w*Wh.w;
          }
      }
      #pragma unroll
      for (int c = 0; c < 2; c++)
        #pragma unroll
        for (int g = 0; g < 4; g++) red[ks][c*4+g][lane] = a[c][g];
      __syncthreads();
      if (tid < Bsz){
        int b = tid;
        #pragma unroll
        for (int c = 0; c < 2; c++){
          int n = n0 + c;
          if (t == 0) cr[c] = c0[(size_t)b*Hn + n];
          float g0 = red[0][c*4+0][b]+red[1][c*4+0][b]+red[2][c*4+0][b]+red[3][c*4+0][b] + bs[c][0];
          float g1 = red[0][c*4+1][b]+red[1][c*4+1][b]+red[2][c*4+1][b]+red[3][c*4+1][b] + bs[c][1];
          float g2 = red[0][c*4+2][b]+red[1][c*4+2][b]+red[2][c*4+2][b]+red[3][c*4+2][b] + bs[c][2];
          float g3 = red[0][c*4+3][b]+red[1][c*4+3][b]+red[2][c*4+3][b]+red[3][c*4+3][b] + bs[c][3];
          float ii = sigf(g0), ff = sigf(g1), gg = tanhf(g2), oo = sigf(g3);
          float cn = ff*cr[c] + ii*gg;
          float hn = oo*tanhf(cn);
          cr[c] = cn;
          scst(hhist + ((size_t)t*Bsz + b)*Hn + n, hn);
          if (t == Tn - 1){
            outp[Tn*Bsz*An + (size_t)b*Hn + n]           = hn;
            outp[Tn*Bsz*An + Bsz*Hn + (size_t)b*Hn + n]  = cn;
          }
        }
      }
    }
    if (t < Tn - 1) gbar(bar+2, bar+3, (int)gridDim.x, ++ph);
  }
}

// ---------- q head ----------
__global__ __launch_bounds__(256) void qout_kernel(
    const float* __restrict__ m, const float* __restrict__ out_W,
    const float* __restrict__ out_b, float* __restrict__ q)
{
  const int t = blockIdx.x;
  for (int p = threadIdx.x; p < Bsz*An; p += 256) {
    int b = p / An, a2 = p % An;
    const float* mr = m + ((size_t)(t*Bsz + b))*Hn;
    const float* wr = out_W + (size_t)a2*Hn;
    float s = out_b[a2];
    #pragma unroll 8
    for (int k = 0; k < Hn; k++) s += mr[k]*wr[k];
    q[((size_t)(t*Bsz + b))*An + a2] = s;
  }
}

extern "C" void kernel_launch(void* const* d_in, const int* in_sizes, int n_in,
                              void* d_out, int out_size, void* d_ws, size_t ws_size,
                              hipStream_t stream) {
  (void)in_sizes; (void)n_in; (void)out_size; (void)ws_size;
  const float* state    = (const float*)d_in[0];
  const float* demo     = (const float*)d_in[1];
  const int*   dlen     = (const int*)  d_in[2];
  const float* h0       = (const float*)d_in[5];
  const float* c0       = (const float*)d_in[6];
  const float* enc_Wih  = (const float*)d_in[7];
  const float* enc_Whh  = (const float*)d_in[8];
  const float* enc_bih  = (const float*)d_in[9];
  const float* enc_bhh  = (const float*)d_in[10];
  const float* attn_W   = (const float*)d_in[11];
  const float* attn_b   = (const float*)d_in[12];
  const float* comb_W   = (const float*)d_in[13];
  const float* comb_b   = (const float*)d_in[14];
  const float* lstm_Wih = (const float*)d_in[15];
  const float* lstm_Whh = (const float*)d_in[16];
  const float* lstm_bih = (const float*)d_in[17];
  const float* lstm_bhh = (const float*)d_in[18];
  const float* mid_W    = (const float*)d_in[19];
  const float* mid_b    = (const float*)d_in[20];
  const float* out_W    = (const float*)d_in[21];
  const float* out_b    = (const float*)d_in[22];
  float* ws   = (float*)d_ws;
  float* qout = (float*)d_out;

  // workspace layout (f32 words) — total ~51.4 MB
  float* attnp  = ws + 0;         // 3,276,800  [B][L][H]
  float* CE     = ws + 3276800;   // 3,276,800  [B][H][L]
  float* preobs = ws + 6553600;   // 2,097,152  [T*B][H]
  float* region = ws + 8650752;   // 4,194,304 shared region:
  float* demoT  = region;                  // enc: 819,200   [L][B][D]
  float* hencR  = region + 819200;         // enc: 3,276,800 [L][B][H]
  float* xrow   = region;                  // dec: 2,097,152 [T][B][H] (aliases demoT+hencR head)
  float* hhist  = region + 2097152;        // dec: 2,097,152 [T][B][H] (aliases hencR tail)
  int*   bar    = (int*)(ws + 12845056);   // 8 ints
  float* mbuf   = CE;             // mid-GEMM out aliases CE (dead after dec)

  hipMemsetAsync((void*)bar, 0, 32, stream);

  demo_transpose_kernel<<<3200, 256, 0, stream>>>(demo, demoT);

  // preobs[(t,b)][n] = state[t,b,:] . comb_W[n, 512:640]
  gemm_nt_kernel<<<dim3(Tn*Bsz/64, Hn/64), 256, 0, stream>>>(
      state, Dn, comb_W + Hn, Hn + Dn, nullptr, preobs, Hn, Dn);

  enc_scan_kernel<<<256, 256, 0, stream>>>(
      demoT, enc_Wih, enc_Whh, enc_bih, enc_bhh, attn_W, attn_b, comb_W,
      hencR, attnp, CE, bar);

  dec_scan_kernel<<<256, 256, 0, stream>>>(
      h0, c0, attnp, CE, preobs, dlen, lstm_Wih, lstm_Whh, lstm_bih, lstm_bhh,
      comb_b, xrow, hhist, qout, bar);

  // m = hhist @ mid_W^T + mid_b   (into aliased CE buffer)
  gemm_nt_kernel<<<dim3(Tn*Bsz/64, Hn/64), 256, 0, stream>>>(
      hhist, Hn, mid_W, Hn, mid_b, mbuf, Hn, Hn);

  qout_kernel<<<Tn, 256, 0, stream>>>(mbuf, out_W, out_b, qout);
}

// Round 6
// 5842.186 us; speedup vs baseline: 1.2119x; 1.2119x over previous
//
#include <hip/hip_runtime.h>
#include <math.h>

#define Bsz 64
#define Tn 64
#define Ln 100
#define Dn 128
#define An 18
#define Hn 512
#define NGRP 16

__device__ __forceinline__ float sigf(float x){ return 1.0f/(1.0f+expf(-x)); }

// write-through agent-scope store (reaches coherence point; no stale dirty line)
__device__ __forceinline__ void scst(float* p, float v){
  __hip_atomic_store(p, v, __ATOMIC_RELAXED, __HIP_MEMORY_SCOPE_AGENT);
}
__device__ __forceinline__ void scsti(int* p, int v){
  __hip_atomic_store(p, v, __ATOMIC_RELAXED, __HIP_MEMORY_SCOPE_AGENT);
}
__device__ __forceinline__ int lcldi(const int* p){
  return __hip_atomic_load((int*)p, __ATOMIC_RELAXED, __HIP_MEMORY_SCOPE_AGENT);
}

// Hierarchical grid barrier: 16 groups x (nb/16) blocks. Counters monotonic,
// each on its own 256B line -> max 16 same-line contenders at any level
// (vs 256 on one line before: same-line far-atomic RMWs serialize ~100ns each,
// which measured as ~28us/barrier). vmcnt(0) drains this block's write-through
// stores to the coherence point before arrival; readers use cached loads of
// write-once addresses, so no acquire fence / L2 invalidate is needed.
__device__ __forceinline__ void gbarH(int* grp_arr, int* grp_gen, int* root,
                                      int nb, int ph){
  __syncthreads();
  if (threadIdx.x == 0){
    asm volatile("s_waitcnt vmcnt(0) lgkmcnt(0)" ::: "memory");
    const int gs = nb >> 4;
    const int g  = (int)blockIdx.x & 15;
    int a = __hip_atomic_fetch_add(grp_arr + g*64, 1, __ATOMIC_RELAXED, __HIP_MEMORY_SCOPE_AGENT) + 1;
    if (a == ph*gs){
      int r = __hip_atomic_fetch_add(root, 1, __ATOMIC_RELAXED, __HIP_MEMORY_SCOPE_AGENT) + 1;
      if (r == ph*NGRP){
        #pragma unroll
        for (int i = 0; i < NGRP; i++) scsti(grp_gen + i*64, ph);
      }
    }
    while (lcldi(grp_gen + g*64) < ph) __builtin_amdgcn_s_sleep(1);
  }
  __syncthreads();
}

// ---------- demo transpose: demoT[l][b][d] = demo[0][b][l][d] ----------
__global__ __launch_bounds__(256) void demo_transpose_kernel(
    const float* __restrict__ demo, float* __restrict__ demoT)
{
  int idx = blockIdx.x*256 + threadIdx.x;   // ((l*64 + b)*128 + d)
  if (idx < Ln*Bsz*Dn) {
    int d = idx & 127;
    int b = (idx >> 7) & 63;
    int l = idx >> 13;
    demoT[idx] = demo[((size_t)(b*Ln + l))*Dn + d];
  }
}

// ---------- generic tiled GEMM: C[M][N] = A[M][K] * B[N][K]^T + bias[n] ----------
__global__ __launch_bounds__(256) void gemm_nt_kernel(
    const float* __restrict__ A, int lda,
    const float* __restrict__ B, int ldb,
    const float* __restrict__ bias,
    float* __restrict__ C, int ldc, int K)
{
  __shared__ float As[64][17];
  __shared__ float Bs[64][17];
  const int m0 = blockIdx.x * 64;
  const int n0 = blockIdx.y * 64;
  const int tx = threadIdx.x & 15;
  const int ty = threadIdx.x >> 4;
  float acc[4][4] = {};
  for (int k0 = 0; k0 < K; k0 += 16) {
    #pragma unroll
    for (int i = 0; i < 4; i++) {
      int e = threadIdx.x + i*256;
      int r = e >> 4, c = e & 15;
      As[r][c] = A[(size_t)(m0 + r)*lda + k0 + c];
      Bs[r][c] = B[(size_t)(n0 + r)*ldb + k0 + c];
    }
    __syncthreads();
    #pragma unroll
    for (int kk = 0; kk < 16; kk++) {
      float a0 = As[ty*4+0][kk], a1 = As[ty*4+1][kk], a2 = As[ty*4+2][kk], a3 = As[ty*4+3][kk];
      float b0 = Bs[tx*4+0][kk], b1 = Bs[tx*4+1][kk], b2 = Bs[tx*4+2][kk], b3 = Bs[tx*4+3][kk];
      acc[0][0] += a0*b0; acc[0][1] += a0*b1; acc[0][2] += a0*b2; acc[0][3] += a0*b3;
      acc[1][0] += a1*b0; acc[1][1] += a1*b1; acc[1][2] += a1*b2; acc[1][3] += a1*b3;
      acc[2][0] += a2*b0; acc[2][1] += a2*b1; acc[2][2] += a2*b2; acc[2][3] += a2*b3;
      acc[3][0] += a3*b0; acc[3][1] += a3*b1; acc[3][2] += a3*b2; acc[3][3] += a3*b3;
    }
    __syncthreads();
  }
  #pragma unroll
  for (int i = 0; i < 4; i++) {
    #pragma unroll
    for (int j = 0; j < 4; j++) {
      int nn = n0 + tx*4 + j;
      float v = acc[i][j] + (bias ? bias[nn] : 0.0f);
      C[(size_t)(m0 + ty*4 + i)*ldc + nn] = v;
    }
  }
}

// ---------- persistent fused encoder: h-scan + attnp + CE, 256 blocks x 2 cols ----------
__global__ __launch_bounds__(256, 1) void enc_scan_kernel(
    const float* __restrict__ demoT,   // [Ln][Bsz][Dn]
    const float* __restrict__ Wih, const float* __restrict__ Whh,
    const float* __restrict__ bih, const float* __restrict__ bhh,
    const float* __restrict__ attn_W, const float* __restrict__ attn_b,
    const float* __restrict__ comb_W,
    float* __restrict__ hencR,         // [Ln][Bsz][Hn]  per-step write-once
    float* __restrict__ attnp,         // [Bsz][Ln][Hn]
    float* __restrict__ CE,            // [Bsz][Hn][Ln]
    int* __restrict__ gA, int* __restrict__ gG, int* __restrict__ gR)
{
  const int bid  = blockIdx.x;
  const int lane = threadIdx.x & 63;
  const int ks   = threadIdx.x >> 6;
  const int n0 = bid*2;

  const float4* whh[8]; const float4* wih[8];
  #pragma unroll
  for (int c = 0; c < 2; c++)
    #pragma unroll
    for (int g = 0; g < 4; g++){
      int r = g*Hn + n0 + c;
      whh[c*4+g] = (const float4*)(Whh + (size_t)r*Hn) + ks*32;
      wih[c*4+g] = (const float4*)(Wih + (size_t)r*Dn) + ks*8;
    }
  const float4* atw[2] = {
    (const float4*)(attn_W + (size_t)(n0+0)*Hn) + ks*32,
    (const float4*)(attn_W + (size_t)(n0+1)*Hn) + ks*32 };
  const float4* cbw[2] = {
    (const float4*)(comb_W + (size_t)(n0+0)*(Hn+Dn)) + ks*32,
    (const float4*)(comb_W + (size_t)(n0+1)*(Hn+Dn)) + ks*32 };

  float bsum[2][4];
  #pragma unroll
  for (int c = 0; c < 2; c++)
    #pragma unroll
    for (int g = 0; g < 4; g++){
      int r = g*Hn + n0 + c;
      bsum[c][g] = bih[r] + bhh[r];
    }
  const float ab[2] = { attn_b[n0], attn_b[n0+1] };
  float cr[2] = {0.f, 0.f};

  __shared__ float red[4][12][Bsz];

  for (int l = 0; l <= Ln; l++){
    float a[2][4] = {{0,0,0,0},{0,0,0,0}};
    float aa[2] = {0,0}, ac[2] = {0,0};
    if (l >= 1){
      const float4* hv = (const float4*)(hencR + ((size_t)(l-1)*Bsz + lane)*Hn) + ks*32;
      #pragma unroll 4
      for (int q = 0; q < 32; q++){
        float4 V = hv[q];
        #pragma unroll
        for (int c = 0; c < 2; c++){
          #pragma unroll
          for (int g = 0; g < 4; g++){
            float4 W = whh[c*4+g][q];
            a[c][g] += V.x*W.x + V.y*W.y + V.z*W.z + V.w*W.w;
          }
          float4 Aw = atw[c][q];
          aa[c] += V.x*Aw.x + V.y*Aw.y + V.z*Aw.z + V.w*Aw.w;
          float4 Cw = cbw[c][q];
          ac[c] += V.x*Cw.x + V.y*Cw.y + V.z*Cw.z + V.w*Cw.w;
        }
      }
    }
    if (l < Ln){
      const float4* dv = (const float4*)(demoT + ((size_t)l*Bsz + lane)*Dn) + ks*8;
      #pragma unroll
      for (int q = 0; q < 8; q++){
        float4 V = dv[q];
        #pragma unroll
        for (int c = 0; c < 2; c++)
          #pragma unroll
          for (int g = 0; g < 4; g++){
            float4 W = wih[c*4+g][q];
            a[c][g] += V.x*W.x + V.y*W.y + V.z*W.z + V.w*W.w;
          }
      }
    }
    #pragma unroll
    for (int c = 0; c < 2; c++){
      #pragma unroll
      for (int g = 0; g < 4; g++) red[ks][c*4+g][lane] = a[c][g];
      red[ks][8+c][lane]  = aa[c];
      red[ks][10+c][lane] = ac[c];
    }
    __syncthreads();
    if (threadIdx.x < Bsz){
      int b = threadIdx.x;
      if (l < Ln){
        #pragma unroll
        for (int c = 0; c < 2; c++){
          float g0 = red[0][c*4+0][b]+red[1][c*4+0][b]+red[2][c*4+0][b]+red[3][c*4+0][b] + bsum[c][0];
          float g1 = red[0][c*4+1][b]+red[1][c*4+1][b]+red[2][c*4+1][b]+red[3][c*4+1][b] + bsum[c][1];
          float g2 = red[0][c*4+2][b]+red[1][c*4+2][b]+red[2][c*4+2][b]+red[3][c*4+2][b] + bsum[c][2];
          float g3 = red[0][c*4+3][b]+red[1][c*4+3][b]+red[2][c*4+3][b]+red[3][c*4+3][b] + bsum[c][3];
          float ii = sigf(g0), ff = sigf(g1), gg = tanhf(g2), oo = sigf(g3);
          float cn = ff*cr[c] + ii*gg;
          float hn = oo*tanhf(cn);
          cr[c] = cn;
          scst(hencR + ((size_t)l*Bsz + b)*Hn + n0 + c, hn);
        }
      }
      if (l >= 1){
        #pragma unroll
        for (int c = 0; c < 2; c++){
          float av = red[0][8+c][b]+red[1][8+c][b]+red[2][8+c][b]+red[3][8+c][b] + ab[c];
          float cv = red[0][10+c][b]+red[1][10+c][b]+red[2][10+c][b]+red[3][10+c][b];
          scst(attnp + ((size_t)(b*Ln + (l-1)))*Hn + n0 + c, av);
          scst(CE + ((size_t)(b*Hn + n0 + c))*Ln + (l-1), cv);
        }
      }
    }
    if (l < Ln) gbarH(gA, gG, gR, (int)gridDim.x, l+1);
  }
}

// ---------- persistent decoder: 256 blocks, 2 phases/step ----------
__global__ __launch_bounds__(256, 1) void dec_scan_kernel(
    const float* __restrict__ h0, const float* __restrict__ c0,
    const float* __restrict__ attnp,   // [Bsz][Ln][Hn]
    const float* __restrict__ CE,      // [Bsz][Hn][Ln]
    const float* __restrict__ preobs,  // [Tn*Bsz][Hn]
    const int*   __restrict__ dlen,
    const float* __restrict__ lstm_Wih, const float* __restrict__ lstm_Whh,
    const float* __restrict__ lstm_bih, const float* __restrict__ lstm_bhh,
    const float* __restrict__ comb_b,
    float* __restrict__ xrow,          // [Tn][Bsz][Hn]  per-step write-once
    float* __restrict__ hhist,         // [Tn][Bsz][Hn]  per-step write-once
    float* __restrict__ outp,
    int* __restrict__ gA, int* __restrict__ gG, int* __restrict__ gR)
{
  const int bid  = blockIdx.x;
  const int tid  = threadIdx.x;
  const int lane = tid & 63;
  const int ks   = tid >> 6;
  const int n0 = bid*2;

  __shared__ float hs[Hn];
  __shared__ float wls[128];
  __shared__ float mx_s, sum_s;
  __shared__ float red[4][8][Bsz];

  const float4* wi[8]; const float4* wh[8];
  #pragma unroll
  for (int c = 0; c < 2; c++)
    #pragma unroll
    for (int g = 0; g < 4; g++){
      int r = g*Hn + n0 + c;
      wi[c*4+g] = (const float4*)(lstm_Wih + (size_t)r*Hn) + ks*32;
      wh[c*4+g] = (const float4*)(lstm_Whh + (size_t)r*Hn) + ks*32;
    }
  float bs[2][4];
  #pragma unroll
  for (int c = 0; c < 2; c++)
    #pragma unroll
    for (int g = 0; g < 4; g++){
      int r = g*Hn + n0 + c;
      bs[c][g] = lstm_bih[r] + lstm_bhh[r];
    }
  float cr[2] = {0.f, 0.f};
  int ph = 0;

  for (int t = 0; t < Tn; t++){
    const float* hprev_all = (t == 0) ? h0 : (hhist + (size_t)(t-1)*Bsz*Hn);

    // ============ Phase 1: attention scores + softmax + x (blocks 0..63) ============
    if (bid < Bsz){
      const int b = bid;
      const float* hrow = hprev_all + (size_t)b*Hn;
      for (int i = tid; i < Hn; i += 256) hs[i] = hrow[i];
      if (tid >= 200 && tid < 228) wls[tid - 100] = -1e30f;
      __syncthreads();
      const int len = dlen[b];
      if (tid < 200){
        int l = tid >> 1, kh = tid & 1;
        const float4* ap = (const float4*)(attnp + ((size_t)(b*Ln + l))*Hn + kh*256);
        const float4* hv = (const float4*)(hs + kh*256);
        float s = 0.f;
        #pragma unroll 8
        for (int k = 0; k < 64; k++){
          float4 A = ap[k], H = hv[k];
          s += A.x*H.x + A.y*H.y + A.z*H.z + A.w*H.w;
        }
        s += __shfl_xor(s, 1);
        if (kh == 0) wls[l] = (l < len) ? s*0.1f : -1e30f;
      }
      __syncthreads();
      if (tid < 64){
        float v = fmaxf(wls[tid], wls[tid+64]);
        for (int off = 1; off < 64; off <<= 1) v = fmaxf(v, __shfl_xor(v, off));
        if (tid == 0) mx_s = v;
      }
      __syncthreads();
      float mx = mx_s;
      if (tid < 64){
        float e0 = (wls[tid]    > -1e29f) ? expf(wls[tid]    - mx) : 0.f;
        float e1 = (wls[tid+64] > -1e29f) ? expf(wls[tid+64] - mx) : 0.f;
        wls[tid] = e0; wls[tid+64] = e1;
        float v = e0 + e1;
        for (int off = 1; off < 64; off <<= 1) v += __shfl_xor(v, off);
        if (tid == 0) sum_s = v;
      }
      __syncthreads();
      float inv = 1.0f / sum_s;
      const float* pr = preobs + ((size_t)(t*Bsz + b))*Hn;
      #pragma unroll
      for (int c2 = 0; c2 < 2; c2++){
        int n = tid + c2*256;
        const float* cer = CE + ((size_t)(b*Hn + n))*Ln;
        float acc = 0.f;
        for (int l2 = 0; l2 < len; ++l2) acc += cer[l2]*wls[l2];
        float v = acc*inv + pr[n] + comb_b[n];
        scst(xrow + ((size_t)t*Bsz + b)*Hn + n, fmaxf(v, 0.f));
      }
    }
    gbarH(gA, gG, gR, (int)gridDim.x, ++ph);

    // ============ Phase 2: gates = Wih@x + Whh@h_prev + bias; cell ============
    {
      float a[2][4] = {{0,0,0,0},{0,0,0,0}};
      const float4* xv = (const float4*)(xrow + ((size_t)t*Bsz + lane)*Hn) + ks*32;
      const float4* hv = (const float4*)(hprev_all + (size_t)lane*Hn) + ks*32;
      #pragma unroll 4
      for (int q = 0; q < 32; q++){
        float4 X = xv[q];
        float4 H = hv[q];
        #pragma unroll
        for (int c = 0; c < 2; c++)
          #pragma unroll
          for (int g = 0; g < 4; g++){
            float4 Wx = wi[c*4+g][q];
            float4 Wh = wh[c*4+g][q];
            a[c][g] += X.x*Wx.x + X.y*Wx.y + X.z*Wx.z + X.w*Wx.w
                     + H.x*Wh.x + H.y*Wh.y + H.z*Wh.z + H.w*Wh.w;
          }
      }
      #pragma unroll
      for (int c = 0; c < 2; c++)
        #pragma unroll
        for (int g = 0; g < 4; g++) red[ks][c*4+g][lane] = a[c][g];
      __syncthreads();
      if (tid < Bsz){
        int b = tid;
        #pragma unroll
        for (int c = 0; c < 2; c++){
          int n = n0 + c;
          if (t == 0) cr[c] = c0[(size_t)b*Hn + n];
          float g0 = red[0][c*4+0][b]+red[1][c*4+0][b]+red[2][c*4+0][b]+red[3][c*4+0][b] + bs[c][0];
          float g1 = red[0][c*4+1][b]+red[1][c*4+1][b]+red[2][c*4+1][b]+red[3][c*4+1][b] + bs[c][1];
          float g2 = red[0][c*4+2][b]+red[1][c*4+2][b]+red[2][c*4+2][b]+red[3][c*4+2][b] + bs[c][2];
          float g3 = red[0][c*4+3][b]+red[1][c*4+3][b]+red[2][c*4+3][b]+red[3][c*4+3][b] + bs[c][3];
          float ii = sigf(g0), ff = sigf(g1), gg = tanhf(g2), oo = sigf(g3);
          float cn = ff*cr[c] + ii*gg;
          float hn = oo*tanhf(cn);
          cr[c] = cn;
          scst(hhist + ((size_t)t*Bsz + b)*Hn + n, hn);
          if (t == Tn - 1){
            outp[Tn*Bsz*An + (size_t)b*Hn + n]           = hn;
            outp[Tn*Bsz*An + Bsz*Hn + (size_t)b*Hn + n]  = cn;
          }
        }
      }
    }
    if (t < Tn - 1) gbarH(gA, gG, gR, (int)gridDim.x, ++ph);
  }
}

// ---------- q head ----------
__global__ __launch_bounds__(256) void qout_kernel(
    const float* __restrict__ m, const float* __restrict__ out_W,
    const float* __restrict__ out_b, float* __restrict__ q)
{
  const int t = blockIdx.x;
  for (int p = threadIdx.x; p < Bsz*An; p += 256) {
    int b = p / An, a2 = p % An;
    const float* mr = m + ((size_t)(t*Bsz + b))*Hn;
    const float* wr = out_W + (size_t)a2*Hn;
    float s = out_b[a2];
    #pragma unroll 8
    for (int k = 0; k < Hn; k++) s += mr[k]*wr[k];
    q[((size_t)(t*Bsz + b))*An + a2] = s;
  }
}

extern "C" void kernel_launch(void* const* d_in, const int* in_sizes, int n_in,
                              void* d_out, int out_size, void* d_ws, size_t ws_size,
                              hipStream_t stream) {
  (void)in_sizes; (void)n_in; (void)out_size; (void)ws_size;
  const float* state    = (const float*)d_in[0];
  const float* demo     = (const float*)d_in[1];
  const int*   dlen     = (const int*)  d_in[2];
  const float* h0       = (const float*)d_in[5];
  const float* c0       = (const float*)d_in[6];
  const float* enc_Wih  = (const float*)d_in[7];
  const float* enc_Whh  = (const float*)d_in[8];
  const float* enc_bih  = (const float*)d_in[9];
  const float* enc_bhh  = (const float*)d_in[10];
  const float* attn_W   = (const float*)d_in[11];
  const float* attn_b   = (const float*)d_in[12];
  const float* comb_W   = (const float*)d_in[13];
  const float* comb_b   = (const float*)d_in[14];
  const float* lstm_Wih = (const float*)d_in[15];
  const float* lstm_Whh = (const float*)d_in[16];
  const float* lstm_bih = (const float*)d_in[17];
  const float* lstm_bhh = (const float*)d_in[18];
  const float* mid_W    = (const float*)d_in[19];
  const float* mid_b    = (const float*)d_in[20];
  const float* out_W    = (const float*)d_in[21];
  const float* out_b    = (const float*)d_in[22];
  float* ws   = (float*)d_ws;
  float* qout = (float*)d_out;

  // workspace layout (f32 words) — total ~51.4 MB + barrier tail
  float* attnp  = ws + 0;         // 3,276,800  [B][L][H]
  float* CE     = ws + 3276800;   // 3,276,800  [B][H][L]
  float* preobs = ws + 6553600;   // 2,097,152  [T*B][H]
  float* region = ws + 8650752;   // 4,194,304 shared region:
  float* demoT  = region;                  // enc: 819,200   [L][B][D]
  float* hencR  = region + 819200;         // enc: 3,276,800 [L][B][H]
  float* xrow   = region;                  // dec: 2,097,152 [T][B][H]
  float* hhist  = region + 2097152;        // dec: 2,097,152 [T][B][H]
  int*   barB   = (int*)(ws + 12845056);
  // enc set: grp_arr[16*64], grp_gen[16*64], root[64]; dec set follows
  int* encA = barB;          int* encG = barB + 1024; int* encR = barB + 2048;
  int* decA = barB + 2112;   int* decG = barB + 3136; int* decR = barB + 4160;
  float* mbuf = CE;               // mid-GEMM out aliases CE (dead after dec)

  hipMemsetAsync((void*)barB, 0, 4224*4, stream);

  demo_transpose_kernel<<<3200, 256, 0, stream>>>(demo, demoT);

  // preobs[(t,b)][n] = state[t,b,:] . comb_W[n, 512:640]
  gemm_nt_kernel<<<dim3(Tn*Bsz/64, Hn/64), 256, 0, stream>>>(
      state, Dn, comb_W + Hn, Hn + Dn, nullptr, preobs, Hn, Dn);

  enc_scan_kernel<<<256, 256, 0, stream>>>(
      demoT, enc_Wih, enc_Whh, enc_bih, enc_bhh, attn_W, attn_b, comb_W,
      hencR, attnp, CE, encA, encG, encR);

  dec_scan_kernel<<<256, 256, 0, stream>>>(
      h0, c0, attnp, CE, preobs, dlen, lstm_Wih, lstm_Whh, lstm_bih, lstm_bhh,
      comb_b, xrow, hhist, qout, decA, decG, decR);

  // m = hhist @ mid_W^T + mid_b   (into aliased CE buffer)
  gemm_nt_kernel<<<dim3(Tn*Bsz/64, Hn/64), 256, 0, stream>>>(
      hhist, Hn, mid_W, Hn, mid_b, mbuf, Hn, Hn);

  qout_kernel<<<Tn, 256, 0, stream>>>(mbuf, out_W, out_b, qout);
}

// Round 7
// 2881.196 us; speedup vs baseline: 2.4573x; 2.0277x over previous
//
#include <hip/hip_runtime.h>
#include <math.h>

#define Bsz 64
#define Tn 64
#define Ln 100
#define Dn 128
#define An 18
#define Hn 512
#define NGRP 16

__device__ __forceinline__ float sigf(float x){ return 1.0f/(1.0f+expf(-x)); }

// write-through agent-scope store (reaches coherence point; no stale dirty line)
__device__ __forceinline__ void scst(float* p, float v){
  __hip_atomic_store(p, v, __ATOMIC_RELAXED, __HIP_MEMORY_SCOPE_AGENT);
}
__device__ __forceinline__ void scsti(int* p, int v){
  __hip_atomic_store(p, v, __ATOMIC_RELAXED, __HIP_MEMORY_SCOPE_AGENT);
}
__device__ __forceinline__ int lcldi(const int* p){
  return __hip_atomic_load((int*)p, __ATOMIC_RELAXED, __HIP_MEMORY_SCOPE_AGENT);
}

// Hierarchical grid barrier (16 groups x 16 blocks, 256B-line-separated counters).
// vmcnt(0) drains this block's write-through stores before arrival; readers use
// cached loads of write-once addresses -> no acquire fence / L2 invalidate.
__device__ __forceinline__ void gbarH(int* grp_arr, int* grp_gen, int* root,
                                      int nb, int ph){
  __syncthreads();
  if (threadIdx.x == 0){
    asm volatile("s_waitcnt vmcnt(0) lgkmcnt(0)" ::: "memory");
    const int gs = nb >> 4;
    const int g  = (int)blockIdx.x & 15;
    int a = __hip_atomic_fetch_add(grp_arr + g*64, 1, __ATOMIC_RELAXED, __HIP_MEMORY_SCOPE_AGENT) + 1;
    if (a == ph*gs){
      int r = __hip_atomic_fetch_add(root, 1, __ATOMIC_RELAXED, __HIP_MEMORY_SCOPE_AGENT) + 1;
      if (r == ph*NGRP){
        #pragma unroll
        for (int i = 0; i < NGRP; i++) scsti(grp_gen + i*64, ph);
      }
    }
    while (lcldi(grp_gen + g*64) < ph) __builtin_amdgcn_s_sleep(1);
  }
  __syncthreads();
}

// ---------- demo transpose: demoT[l][b][d] = demo[0][b][l][d] ----------
__global__ __launch_bounds__(256) void demo_transpose_kernel(
    const float* __restrict__ demo, float* __restrict__ demoT)
{
  int idx = blockIdx.x*256 + threadIdx.x;   // ((l*64 + b)*128 + d)
  if (idx < Ln*Bsz*Dn) {
    int d = idx & 127;
    int b = (idx >> 7) & 63;
    int l = idx >> 13;
    demoT[idx] = demo[((size_t)(b*Ln + l))*Dn + d];
  }
}

// ---------- generic tiled GEMM: C[M][N] = A[M][K] * B[N][K]^T + bias[n] ----------
__global__ __launch_bounds__(256) void gemm_nt_kernel(
    const float* __restrict__ A, int lda,
    const float* __restrict__ B, int ldb,
    const float* __restrict__ bias,
    float* __restrict__ C, int ldc, int K)
{
  __shared__ float As[64][17];
  __shared__ float Bs[64][17];
  const int m0 = blockIdx.x * 64;
  const int n0 = blockIdx.y * 64;
  const int tx = threadIdx.x & 15;
  const int ty = threadIdx.x >> 4;
  float acc[4][4] = {};
  for (int k0 = 0; k0 < K; k0 += 16) {
    #pragma unroll
    for (int i = 0; i < 4; i++) {
      int e = threadIdx.x + i*256;
      int r = e >> 4, c = e & 15;
      As[r][c] = A[(size_t)(m0 + r)*lda + k0 + c];
      Bs[r][c] = B[(size_t)(n0 + r)*ldb + k0 + c];
    }
    __syncthreads();
    #pragma unroll
    for (int kk = 0; kk < 16; kk++) {
      float a0 = As[ty*4+0][kk], a1 = As[ty*4+1][kk], a2 = As[ty*4+2][kk], a3 = As[ty*4+3][kk];
      float b0 = Bs[tx*4+0][kk], b1 = Bs[tx*4+1][kk], b2 = Bs[tx*4+2][kk], b3 = Bs[tx*4+3][kk];
      acc[0][0] += a0*b0; acc[0][1] += a0*b1; acc[0][2] += a0*b2; acc[0][3] += a0*b3;
      acc[1][0] += a1*b0; acc[1][1] += a1*b1; acc[1][2] += a1*b2; acc[1][3] += a1*b3;
      acc[2][0] += a2*b0; acc[2][1] += a2*b1; acc[2][2] += a2*b2; acc[2][3] += a2*b3;
      acc[3][0] += a3*b0; acc[3][1] += a3*b1; acc[3][2] += a3*b2; acc[3][3] += a3*b3;
    }
    __syncthreads();
  }
  #pragma unroll
  for (int i = 0; i < 4; i++) {
    #pragma unroll
    for (int j = 0; j < 4; j++) {
      int nn = n0 + tx*4 + j;
      float v = acc[i][j] + (bias ? bias[nn] : 0.0f);
      C[(size_t)(m0 + ty*4 + i)*ldc + nn] = v;
    }
  }
}

// ---------- persistent fused encoder: 256 blocks x 512 threads, LDS weights ----------
__global__ __launch_bounds__(512, 1) void enc_scan_kernel(
    const float* __restrict__ demoT,   // [Ln][Bsz][Dn]
    const float* __restrict__ Wih, const float* __restrict__ Whh,
    const float* __restrict__ bih, const float* __restrict__ bhh,
    const float* __restrict__ attn_W, const float* __restrict__ attn_b,
    const float* __restrict__ comb_W,
    float* __restrict__ hencR,         // [Ln][Bsz][Hn]  per-step write-once
    float* __restrict__ attnp,         // [Bsz][Ln][Hn]
    float* __restrict__ CE,            // [Bsz][Ln][Hn]
    int* __restrict__ gA, int* __restrict__ gG, int* __restrict__ gR)
{
  const int bid  = blockIdx.x;
  const int tid  = threadIdx.x;
  const int lane = tid & 63;
  const int ks   = tid >> 6;          // 0..7
  const int n0   = bid*2;

  __shared__ float lds_whh[8][Hn];    // 16 KB  rows [c*4+g]
  __shared__ float lds_wih[8][Dn];    //  4 KB
  __shared__ float lds_atw[2][Hn];    //  4 KB
  __shared__ float lds_cbw[2][Hn];    //  4 KB
  __shared__ float red[8][12][Bsz];   // 24 KB

  #pragma unroll
  for (int c = 0; c < 2; c++)
    #pragma unroll
    for (int g = 0; g < 4; g++){
      int r = c*4 + g;
      lds_whh[r][tid] = Whh[(size_t)(g*Hn + n0 + c)*Hn + tid];
      if (tid < Dn) lds_wih[r][tid] = Wih[(size_t)(g*Hn + n0 + c)*Dn + tid];
    }
  #pragma unroll
  for (int c = 0; c < 2; c++){
    lds_atw[c][tid] = attn_W[(size_t)(n0 + c)*Hn + tid];
    lds_cbw[c][tid] = comb_W[(size_t)(n0 + c)*(Hn + Dn) + tid];
  }
  float bsum[2][4];
  #pragma unroll
  for (int c = 0; c < 2; c++)
    #pragma unroll
    for (int g = 0; g < 4; g++){
      int r = g*Hn + n0 + c;
      bsum[c][g] = bih[r] + bhh[r];
    }
  const float ab[2] = { attn_b[n0], attn_b[n0+1] };
  float cr[2] = {0.f, 0.f};
  __syncthreads();

  for (int l = 0; l <= Ln; l++){
    float a[2][4] = {{0,0,0,0},{0,0,0,0}};
    float aa[2] = {0,0}, ac[2] = {0,0};
    if (l >= 1){
      const float4* hv = (const float4*)(hencR + ((size_t)(l-1)*Bsz + lane)*Hn) + ks*16;
      #pragma unroll 4
      for (int q = 0; q < 16; q++){
        float4 H = hv[q];
        #pragma unroll
        for (int c = 0; c < 2; c++){
          #pragma unroll
          for (int g = 0; g < 4; g++){
            float4 W = *(const float4*)&lds_whh[c*4+g][ks*64 + 4*q];
            a[c][g] += H.x*W.x + H.y*W.y + H.z*W.z + H.w*W.w;
          }
          float4 Aw = *(const float4*)&lds_atw[c][ks*64 + 4*q];
          aa[c] += H.x*Aw.x + H.y*Aw.y + H.z*Aw.z + H.w*Aw.w;
          float4 Cw = *(const float4*)&lds_cbw[c][ks*64 + 4*q];
          ac[c] += H.x*Cw.x + H.y*Cw.y + H.z*Cw.z + H.w*Cw.w;
        }
      }
    }
    if (l < Ln){
      const float4* dv = (const float4*)(demoT + ((size_t)l*Bsz + lane)*Dn) + ks*4;
      #pragma unroll
      for (int q = 0; q < 4; q++){
        float4 V = dv[q];
        #pragma unroll
        for (int c = 0; c < 2; c++)
          #pragma unroll
          for (int g = 0; g < 4; g++){
            float4 W = *(const float4*)&lds_wih[c*4+g][ks*16 + 4*q];
            a[c][g] += V.x*W.x + V.y*W.y + V.z*W.z + V.w*W.w;
          }
      }
    }
    #pragma unroll
    for (int c = 0; c < 2; c++){
      #pragma unroll
      for (int g = 0; g < 4; g++) red[ks][c*4+g][lane] = a[c][g];
      red[ks][8+c][lane]  = aa[c];
      red[ks][10+c][lane] = ac[c];
    }
    __syncthreads();
    if (tid < Bsz){
      int b = tid;
      if (l < Ln){
        #pragma unroll
        for (int c = 0; c < 2; c++){
          float g0 = bsum[c][0], g1 = bsum[c][1], g2 = bsum[c][2], g3 = bsum[c][3];
          #pragma unroll
          for (int k = 0; k < 8; k++){
            g0 += red[k][c*4+0][b]; g1 += red[k][c*4+1][b];
            g2 += red[k][c*4+2][b]; g3 += red[k][c*4+3][b];
          }
          float ii = sigf(g0), ff = sigf(g1), gg = tanhf(g2), oo = sigf(g3);
          float cn = ff*cr[c] + ii*gg;
          float hn = oo*tanhf(cn);
          cr[c] = cn;
          scst(hencR + ((size_t)l*Bsz + b)*Hn + n0 + c, hn);
        }
      }
      if (l >= 1){
        #pragma unroll
        for (int c = 0; c < 2; c++){
          float av = ab[c], cv = 0.f;
          #pragma unroll
          for (int k = 0; k < 8; k++){ av += red[k][8+c][b]; cv += red[k][10+c][b]; }
          scst(attnp + ((size_t)(b*Ln + (l-1)))*Hn + n0 + c, av);
          scst(CE    + ((size_t)(b*Ln + (l-1)))*Hn + n0 + c, cv);
        }
      }
    }
    if (l < Ln) gbarH(gA, gG, gR, (int)gridDim.x, l+1);
  }
}

// ---------- persistent decoder: 256 blocks x 512 threads, LDS weights ----------
__global__ __launch_bounds__(512, 1) void dec_scan_kernel(
    const float* __restrict__ h0, const float* __restrict__ c0,
    const float* __restrict__ attnp,   // [Bsz][Ln][Hn]
    const float* __restrict__ CE,      // [Bsz][Ln][Hn]
    const float* __restrict__ preobs,  // [Tn*Bsz][Hn]
    const int*   __restrict__ dlen,
    const float* __restrict__ lstm_Wih, const float* __restrict__ lstm_Whh,
    const float* __restrict__ lstm_bih, const float* __restrict__ lstm_bhh,
    const float* __restrict__ comb_b,
    float* __restrict__ xrow,          // [Tn][Bsz][Hn]  per-step write-once
    float* __restrict__ hhist,         // [Tn][Bsz][Hn]  per-step write-once
    float* __restrict__ outp,
    int* __restrict__ gA, int* __restrict__ gG, int* __restrict__ gR)
{
  const int bid  = blockIdx.x;
  const int tid  = threadIdx.x;
  const int lane = tid & 63;
  const int ks   = tid >> 6;          // 0..7
  const int n0   = bid*2;

  __shared__ float lds_wi[8][Hn];     // 16 KB
  __shared__ float lds_wh[8][Hn];     // 16 KB
  __shared__ float hs[Hn];
  __shared__ float wls[128];
  __shared__ float mx_s, sum_s;
  __shared__ float red[8][8][Bsz];    // 16 KB

  #pragma unroll
  for (int c = 0; c < 2; c++)
    #pragma unroll
    for (int g = 0; g < 4; g++){
      int r = c*4 + g;
      lds_wi[r][tid] = lstm_Wih[(size_t)(g*Hn + n0 + c)*Hn + tid];
      lds_wh[r][tid] = lstm_Whh[(size_t)(g*Hn + n0 + c)*Hn + tid];
    }
  float bs[2][4];
  #pragma unroll
  for (int c = 0; c < 2; c++)
    #pragma unroll
    for (int g = 0; g < 4; g++){
      int r = g*Hn + n0 + c;
      bs[c][g] = lstm_bih[r] + lstm_bhh[r];
    }
  float cr[2] = {0.f, 0.f};
  int ph = 0;
  __syncthreads();

  for (int t = 0; t < Tn; t++){
    const float* hprev_all = (t == 0) ? h0 : (hhist + (size_t)(t-1)*Bsz*Hn);

    // ============ Phase 1: attention (blocks 0..63) + Whh@h partial (ALL) ============
    if (bid < Bsz){
      const int b = bid;
      hs[tid] = hprev_all[(size_t)b*Hn + tid];
      if (tid >= 100 && tid < 128) wls[tid] = -1e30f;
      __syncthreads();
      const int len = dlen[b];
      if (tid < 400){
        int l = tid >> 2, kh = tid & 3;
        const float4* ap = (const float4*)(attnp + ((size_t)(b*Ln + l))*Hn) + kh*32;
        const float4* hv = (const float4*)hs + kh*32;
        float s = 0.f;
        #pragma unroll 8
        for (int k = 0; k < 32; k++){
          float4 A = ap[k], H = hv[k];
          s += A.x*H.x + A.y*H.y + A.z*H.z + A.w*H.w;
        }
        s += __shfl_xor(s, 1);
        s += __shfl_xor(s, 2);
        if (kh == 0) wls[l] = (l < len) ? s*0.1f : -1e30f;
      }
      __syncthreads();
      if (tid < 64){
        float v = fmaxf(wls[tid], wls[tid+64]);
        for (int off = 1; off < 64; off <<= 1) v = fmaxf(v, __shfl_xor(v, off));
        if (tid == 0) mx_s = v;
      }
      __syncthreads();
      float mx = mx_s;
      if (tid < 64){
        float e0 = (wls[tid]    > -1e29f) ? expf(wls[tid]    - mx) : 0.f;
        float e1 = (wls[tid+64] > -1e29f) ? expf(wls[tid+64] - mx) : 0.f;
        wls[tid] = e0; wls[tid+64] = e1;
        float v = e0 + e1;
        for (int off = 1; off < 64; off <<= 1) v += __shfl_xor(v, off);
        if (tid == 0) sum_s = v;
      }
      __syncthreads();
      float inv = 1.0f / sum_s;
      {
        int n = tid;
        const float* cb = CE + (size_t)b*Ln*Hn + n;
        float acc = 0.f;
        for (int l2 = 0; l2 < len; ++l2) acc += cb[(size_t)l2*Hn]*wls[l2];
        float v = acc*inv + preobs[((size_t)(t*Bsz + b))*Hn + n] + comb_b[n];
        scst(xrow + ((size_t)t*Bsz + b)*Hn + n, fmaxf(v, 0.f));
      }
    }
    // all blocks: Whh @ h(t-1) partial for own 2 columns; kept in VGPRs across barrier
    float hpa[2][4] = {{0,0,0,0},{0,0,0,0}};
    {
      const float4* hv = (const float4*)(hprev_all + (size_t)lane*Hn) + ks*16;
      #pragma unroll 4
      for (int q = 0; q < 16; q++){
        float4 H = hv[q];
        #pragma unroll
        for (int c = 0; c < 2; c++)
          #pragma unroll
          for (int g = 0; g < 4; g++){
            float4 W = *(const float4*)&lds_wh[c*4+g][ks*64 + 4*q];
            hpa[c][g] += H.x*W.x + H.y*W.y + H.z*W.z + H.w*W.w;
          }
      }
    }
    gbarH(gA, gG, gR, (int)gridDim.x, ++ph);

    // ============ Phase 2: += Wih@x; reduce; cell ============
    {
      const float4* xv = (const float4*)(xrow + ((size_t)t*Bsz + lane)*Hn) + ks*16;
      #pragma unroll 4
      for (int q = 0; q < 16; q++){
        float4 X = xv[q];
        #pragma unroll
        for (int c = 0; c < 2; c++)
          #pragma unroll
          for (int g = 0; g < 4; g++){
            float4 W = *(const float4*)&lds_wi[c*4+g][ks*64 + 4*q];
            hpa[c][g] += X.x*W.x + X.y*W.y + X.z*W.z + X.w*W.w;
          }
      }
      #pragma unroll
      for (int c = 0; c < 2; c++)
        #pragma unroll
        for (int g = 0; g < 4; g++) red[ks][c*4+g][lane] = hpa[c][g];
      __syncthreads();
      if (tid < Bsz){
        int b = tid;
        #pragma unroll
        for (int c = 0; c < 2; c++){
          int n = n0 + c;
          if (t == 0) cr[c] = c0[(size_t)b*Hn + n];
          float g0 = bs[c][0], g1 = bs[c][1], g2 = bs[c][2], g3 = bs[c][3];
          #pragma unroll
          for (int k = 0; k < 8; k++){
            g0 += red[k][c*4+0][b]; g1 += red[k][c*4+1][b];
            g2 += red[k][c*4+2][b]; g3 += red[k][c*4+3][b];
          }
          float ii = sigf(g0), ff = sigf(g1), gg = tanhf(g2), oo = sigf(g3);
          float cn = ff*cr[c] + ii*gg;
          float hn = oo*tanhf(cn);
          cr[c] = cn;
          scst(hhist + ((size_t)t*Bsz + b)*Hn + n, hn);
          if (t == Tn - 1){
            outp[Tn*Bsz*An + (size_t)b*Hn + n]           = hn;
            outp[Tn*Bsz*An + Bsz*Hn + (size_t)b*Hn + n]  = cn;
          }
        }
      }
    }
    if (t < Tn - 1) gbarH(gA, gG, gR, (int)gridDim.x, ++ph);
  }
}

// ---------- q head ----------
__global__ __launch_bounds__(256) void qout_kernel(
    const float* __restrict__ m, const float* __restrict__ out_W,
    const float* __restrict__ out_b, float* __restrict__ q)
{
  const int t = blockIdx.x;
  for (int p = threadIdx.x; p < Bsz*An; p += 256) {
    int b = p / An, a2 = p % An;
    const float* mr = m + ((size_t)(t*Bsz + b))*Hn;
    const float* wr = out_W + (size_t)a2*Hn;
    float s = out_b[a2];
    #pragma unroll 8
    for (int k = 0; k < Hn; k++) s += mr[k]*wr[k];
    q[((size_t)(t*Bsz + b))*An + a2] = s;
  }
}

extern "C" void kernel_launch(void* const* d_in, const int* in_sizes, int n_in,
                              void* d_out, int out_size, void* d_ws, size_t ws_size,
                              hipStream_t stream) {
  (void)in_sizes; (void)n_in; (void)out_size; (void)ws_size;
  const float* state    = (const float*)d_in[0];
  const float* demo     = (const float*)d_in[1];
  const int*   dlen     = (const int*)  d_in[2];
  const float* h0       = (const float*)d_in[5];
  const float* c0       = (const float*)d_in[6];
  const float* enc_Wih  = (const float*)d_in[7];
  const float* enc_Whh  = (const float*)d_in[8];
  const float* enc_bih  = (const float*)d_in[9];
  const float* enc_bhh  = (const float*)d_in[10];
  const float* attn_W   = (const float*)d_in[11];
  const float* attn_b   = (const float*)d_in[12];
  const float* comb_W   = (const float*)d_in[13];
  const float* comb_b   = (const float*)d_in[14];
  const float* lstm_Wih = (const float*)d_in[15];
  const float* lstm_Whh = (const float*)d_in[16];
  const float* lstm_bih = (const float*)d_in[17];
  const float* lstm_bhh = (const float*)d_in[18];
  const float* mid_W    = (const float*)d_in[19];
  const float* mid_b    = (const float*)d_in[20];
  const float* out_W    = (const float*)d_in[21];
  const float* out_b    = (const float*)d_in[22];
  float* ws   = (float*)d_ws;
  float* qout = (float*)d_out;

  // workspace layout (f32 words)
  float* attnp  = ws + 0;         // 3,276,800  [B][L][H]
  float* CE     = ws + 3276800;   // 3,276,800  [B][L][H]
  float* preobs = ws + 6553600;   // 2,097,152  [T*B][H]
  float* region = ws + 8650752;   // 4,194,304 shared region:
  float* demoT  = region;                  // enc: 819,200   [L][B][D]
  float* hencR  = region + 819200;         // enc: 3,276,800 [L][B][H]
  float* xrow   = region;                  // dec: 2,097,152 [T][B][H]
  float* hhist  = region + 2097152;        // dec: 2,097,152 [T][B][H]
  int*   barB   = (int*)(ws + 12845056);
  int* encA = barB;          int* encG = barB + 1024; int* encR = barB + 2048;
  int* decA = barB + 2112;   int* decG = barB + 3136; int* decR = barB + 4160;
  float* mbuf = CE;               // mid-GEMM out aliases CE (dead after dec)

  hipMemsetAsync((void*)barB, 0, 4224*4, stream);

  demo_transpose_kernel<<<3200, 256, 0, stream>>>(demo, demoT);

  // preobs[(t,b)][n] = state[t,b,:] . comb_W[n, 512:640]
  gemm_nt_kernel<<<dim3(Tn*Bsz/64, Hn/64), 256, 0, stream>>>(
      state, Dn, comb_W + Hn, Hn + Dn, nullptr, preobs, Hn, Dn);

  enc_scan_kernel<<<256, 512, 0, stream>>>(
      demoT, enc_Wih, enc_Whh, enc_bih, enc_bhh, attn_W, attn_b, comb_W,
      hencR, attnp, CE, encA, encG, encR);

  dec_scan_kernel<<<256, 512, 0, stream>>>(
      h0, c0, attnp, CE, preobs, dlen, lstm_Wih, lstm_Whh, lstm_bih, lstm_bhh,
      comb_b, xrow, hhist, qout, decA, decG, decR);

  // m = hhist @ mid_W^T + mid_b   (into aliased CE buffer)
  gemm_nt_kernel<<<dim3(Tn*Bsz/64, Hn/64), 256, 0, stream>>>(
      hhist, Hn, mid_W, Hn, mid_b, mbuf, Hn, Hn);

  qout_kernel<<<Tn, 256, 0, stream>>>(mbuf, out_W, out_b, qout);
}